// Round 1
// baseline (245.787 us; speedup 1.0000x reference)
//
#include <hip/hip_runtime.h>

// WaveNet fused kernel for MI355X (gfx950).
// L=10 layers of pointwise convs (C=128), B=4, T=32768.
// Strategy: bf16 MFMA (16x16x32), one block per 128-column tile, whole layer
// stack fused; skip & h accumulate in fp32 registers; activations in swizzled
// LDS; weights pre-converted (and pre-swizzled for LDS-staged ones) into d_ws.

typedef __bf16 bf16x8 __attribute__((ext_vector_type(8)));
typedef float  f32x4  __attribute__((ext_vector_type(4)));
typedef unsigned int uint;
typedef unsigned long long u64;
typedef unsigned short u16;

#define MFMA16(a, b, c) __builtin_amdgcn_mfma_f32_16x16x32_bf16((a), (b), (c), 0, 0, 0)

__device__ __forceinline__ u16 f2bf(float f) {
    uint u = __float_as_uint(f);
    u += 0x7fffu + ((u >> 16) & 1u);   // RNE
    return (u16)(u >> 16);
}
__device__ __forceinline__ float bf2f(u16 s) {
    return __uint_as_float(((uint)s) << 16);
}
__device__ __forceinline__ u64 pack4(f32x4 v) {
    return (u64)f2bf(v[0]) | ((u64)f2bf(v[1]) << 16) |
           ((u64)f2bf(v[2]) << 32) | ((u64)f2bf(v[3]) << 48);
}

// ---------------------------------------------------------------------------
// Weight conversion: fp32 -> bf16 into d_ws.
// Slot layout (16384 bf16 each): 0..9 Wd (swizzled), 10..19 Wr (RAW, read
// direct from global), 20..29 Ws (swizzled), 30 Wf1 (swz), 31 Wf2 (swz).
// Swizzle: LDS image byte a (row r = a>>8) holds W[r][ (off ^ ((r&7)<<4))>>1 ]
// so that a LINEAR global_load_lds copy yields the bank-conflict-free layout.
// ---------------------------------------------------------------------------
__global__ void convert_weights(const float* __restrict__ Wd,
                                const float* __restrict__ Wr,
                                const float* __restrict__ Ws,
                                const float* __restrict__ Wf1,
                                const float* __restrict__ Wf2,
                                u16* __restrict__ wsb) {
    int idx = blockIdx.x * 256 + threadIdx.x;
    if (idx >= 32 * 16384) return;
    int slot = idx >> 14;
    int a2   = idx & 16383;
    int r    = a2 >> 7;     // row (output channel)
    int c    = a2 & 127;    // bf16 column index within row
    const float* src;
    bool swz = true;
    if (slot < 10)       { src = Wd  + slot * 16384; }
    else if (slot < 20)  { src = Wr  + (slot - 10) * 16384; swz = false; }
    else if (slot < 30)  { src = Ws  + (slot - 20) * 16384; }
    else if (slot == 30) { src = Wf1; }
    else                 { src = Wf2; }
    int cs = swz ? (c ^ ((r & 7) << 3)) : c;
    wsb[idx] = f2bf(src[r * 128 + cs]);
}

// ---------------------------------------------------------------------------
// Main fused kernel. Grid: 1024 blocks (4 batches * 256 tiles), 256 threads.
// LDS: s_act 32KB  = Act[col 128][chan 128] bf16, byte ^= (col&7)<<4 swizzle
//      s_wst 32KB  = staged weight matrix (pre-swizzled image, linear copy)
// ---------------------------------------------------------------------------
__device__ __forceinline__ bf16x8 ldfrag(const unsigned char* s, int rc, int ks, int hi) {
    // 16B fragment: element (rc, k) k = 32*ks + 8*hi .. +7
    int byte = rc * 256 + (((ks << 6) + (hi << 4)) ^ ((rc & 7) << 4));
    return *(const bf16x8*)(s + byte);
}

__device__ __forceinline__ void stage_w(const u16* __restrict__ gsrc,
                                        unsigned char* lds, int wid, int lane) {
    // copy 32768 bytes linearly; wave w does 1KB chunks w*8 .. w*8+7
#pragma unroll
    for (int i = 0; i < 8; ++i) {
        int chunk = wid * 8 + i;
        const u16* g = gsrc + chunk * 512 + lane * 8;   // per-lane 16B source
        __builtin_amdgcn_global_load_lds(
            (const __attribute__((address_space(1))) uint*)g,
            (__attribute__((address_space(3))) uint*)(lds + chunk * 1024),
            16, 0, 0);
    }
}

__global__ __launch_bounds__(256, 2)
void wavenet_main(const float* __restrict__ x,
                  const u16* __restrict__ wsb,
                  const float* __restrict__ bd,
                  const float* __restrict__ br,
                  const float* __restrict__ bs,
                  const float* __restrict__ bf1,
                  const float* __restrict__ bf2,
                  float* __restrict__ partial) {
    __shared__ __align__(16) unsigned char s_act[32768];
    __shared__ __align__(16) unsigned char s_wst[32768];
    __shared__ float s_red[2][128];

    const int tid  = threadIdx.x;
    const int lane = tid & 63;
    const int wid  = tid >> 6;
    const int wr   = wid >> 1;      // wave row  (0..1): rows   wr*64..+63
    const int wc   = wid & 1;       // wave col  (0..1): cols   wc*64..+63
    const int lo   = lane & 15;
    const int hi   = lane >> 4;

    const int blk = blockIdx.x;
    const int b   = blk >> 8;               // 256 tiles per batch
    const int t0  = (blk & 255) * 128;

    // ---- issue stage of Wd_0 (async), then stage x tile into s_act --------
    stage_w(wsb + 0 * 16384, s_wst, wid, lane);

    {
        const float* xb = x + (size_t)b * (128u * 32768u) + t0;
#pragma unroll
        for (int i = 0; i < 16; ++i) {
            int task = wid * 16 + i;        // 64 tasks: 32 chan-groups x 2 t-chunks
            int tc = task & 1;
            int cg = task >> 1;
            int t  = tc * 64 + lane;        // col in tile
            int c0 = cg * 4;
            float v0 = xb[(c0 + 0) * 32768 + t];
            float v1 = xb[(c0 + 1) * 32768 + t];
            float v2 = xb[(c0 + 2) * 32768 + t];
            float v3 = xb[(c0 + 3) * 32768 + t];
            u64 pk = (u64)f2bf(v0) | ((u64)f2bf(v1) << 16) |
                     ((u64)f2bf(v2) << 32) | ((u64)f2bf(v3) << 48);
            int byte = t * 256 + ((c0 * 2) ^ ((t & 7) << 4));
            *(u64*)(s_act + byte) = pk;
        }
    }

    // skip accumulator (fp32, persistent across layers)
    f32x4 sk[4][4];
#pragma unroll
    for (int m = 0; m < 4; ++m)
#pragma unroll
        for (int n = 0; n < 4; ++n) { f32x4 z = {0.f, 0.f, 0.f, 0.f}; sk[m][n] = z; }

    __syncthreads();    // x staged, Wd0 ready (barrier drains vmcnt+lgkmcnt)

    f32x4 h_acc[4][4];

#pragma unroll 1
    for (int l = 0; l < 10; ++l) {
        // --- GEMM1: out = Wd . h + bd  (A = s_wst, B = s_act) -------------
        f32x4 bdv[4];
#pragma unroll
        for (int m = 0; m < 4; ++m)
            bdv[m] = *(const f32x4*)(bd + l * 128 + wr * 64 + m * 16 + hi * 4);

        f32x4 out[4][4];
#pragma unroll
        for (int m = 0; m < 4; ++m)
#pragma unroll
            for (int n = 0; n < 4; ++n) out[m][n] = bdv[m];

#pragma unroll
        for (int ks = 0; ks < 4; ++ks) {
            bf16x8 A[4];
#pragma unroll
            for (int m = 0; m < 4; ++m) A[m] = ldfrag(s_wst, wr * 64 + m * 16 + lo, ks, hi);
#pragma unroll
            for (int n = 0; n < 4; ++n) {
                bf16x8 B = ldfrag(s_act, wc * 64 + n * 16 + lo, ks, hi);
#pragma unroll
                for (int m = 0; m < 4; ++m) out[m][n] = MFMA16(A[m], B, out[m][n]);
            }
        }
        __syncthreads();                        // all reads of h & Wd done

        // issue stage of Ws_l over Wd (reads completed at barrier)
        stage_w(wsb + (20 + l) * 16384, s_wst, wid, lane);

        // read h (C-init for residual GEMM) from own region, then overwrite
        // with out (bf16, bias already folded in).
        u64 hv[4][4];
#pragma unroll
        for (int m = 0; m < 4; ++m)
#pragma unroll
            for (int n = 0; n < 4; ++n) {
                int col  = wc * 64 + n * 16 + lo;
                int rowb = (wr * 64 + m * 16 + hi * 4) * 2;
                int byte = col * 256 + (rowb ^ ((col & 7) << 4));
                hv[m][n] = *(const u64*)(s_act + byte);
            }
        asm volatile("" ::: "memory");          // keep reads before writes
#pragma unroll
        for (int m = 0; m < 4; ++m)
#pragma unroll
            for (int n = 0; n < 4; ++n) {
                int col  = wc * 64 + n * 16 + lo;
                int rowb = (wr * 64 + m * 16 + hi * 4) * 2;
                int byte = col * 256 + (rowb ^ ((col & 7) << 4));
                *(u64*)(s_act + byte) = pack4(out[m][n]);
            }
#pragma unroll
        for (int m = 0; m < 4; ++m)
#pragma unroll
            for (int n = 0; n < 4; ++n) {
                f32x4 h;
                h[0] = bf2f((u16)(hv[m][n]      ));
                h[1] = bf2f((u16)(hv[m][n] >> 16));
                h[2] = bf2f((u16)(hv[m][n] >> 32));
                h[3] = bf2f((u16)(hv[m][n] >> 48));
                h_acc[m][n] = h;
            }
        __syncthreads();                        // out visible, Ws staged

        // --- paired GEMM2/3: sk += Ws.out ; h += Wr.out (B shared) --------
        const u16* wrp = wsb + (10 + l) * 16384;  // Wr raw (direct global A)
#pragma unroll
        for (int ks = 0; ks < 4; ++ks) {
            bf16x8 Aw[4], Ar[4];
#pragma unroll
            for (int m = 0; m < 4; ++m) {
                int row = wr * 64 + m * 16 + lo;
                Aw[m] = ldfrag(s_wst, row, ks, hi);
                Ar[m] = *(const bf16x8*)(wrp + row * 128 + ks * 32 + hi * 8);
            }
#pragma unroll
            for (int n = 0; n < 4; ++n) {
                bf16x8 B = ldfrag(s_act, wc * 64 + n * 16 + lo, ks, hi);
#pragma unroll
                for (int m = 0; m < 4; ++m) {
                    sk[m][n]    = MFMA16(Aw[m], B, sk[m][n]);
                    h_acc[m][n] = MFMA16(Ar[m], B, h_acc[m][n]);
                }
            }
        }
        // per-layer biases: skip += bs, h += br
#pragma unroll
        for (int m = 0; m < 4; ++m) {
            f32x4 bsv = *(const f32x4*)(bs + l * 128 + wr * 64 + m * 16 + hi * 4);
            f32x4 brv = *(const f32x4*)(br + l * 128 + wr * 64 + m * 16 + hi * 4);
#pragma unroll
            for (int n = 0; n < 4; ++n) { sk[m][n] += bsv; h_acc[m][n] += brv; }
        }
        __syncthreads();                        // Ws & out reads done

        if (l < 9) {
            stage_w(wsb + (l + 1) * 16384, s_wst, wid, lane);   // Wd_{l+1}
            // write h (bf16) back to act
#pragma unroll
            for (int m = 0; m < 4; ++m)
#pragma unroll
                for (int n = 0; n < 4; ++n) {
                    int col  = wc * 64 + n * 16 + lo;
                    int rowb = (wr * 64 + m * 16 + hi * 4) * 2;
                    int byte = col * 256 + (rowb ^ ((col & 7) << 4));
                    *(u64*)(s_act + byte) = pack4(h_acc[m][n]);
                }
            __syncthreads();                    // h visible, Wd ready
        }
    }

    // ---- final conv head --------------------------------------------------
    // act currently holds out_9 (reads all done). Write relu(skip) into act.
    stage_w(wsb + 30 * 16384, s_wst, wid, lane);       // Wf1
#pragma unroll
    for (int m = 0; m < 4; ++m)
#pragma unroll
        for (int n = 0; n < 4; ++n) {
            f32x4 v;
#pragma unroll
            for (int r = 0; r < 4; ++r) v[r] = fmaxf(sk[m][n][r], 0.f);
            int col  = wc * 64 + n * 16 + lo;
            int rowb = (wr * 64 + m * 16 + hi * 4) * 2;
            int byte = col * 256 + (rowb ^ ((col & 7) << 4));
            *(u64*)(s_act + byte) = pack4(v);
        }
    __syncthreads();

    // GEMM f1: g1 = relu(Wf1 . rs + bf1)
    f32x4 g1[4][4];
#pragma unroll
    for (int m = 0; m < 4; ++m) {
        f32x4 bv = *(const f32x4*)(bf1 + wr * 64 + m * 16 + hi * 4);
#pragma unroll
        for (int n = 0; n < 4; ++n) g1[m][n] = bv;
    }
#pragma unroll
    for (int ks = 0; ks < 4; ++ks) {
        bf16x8 A[4];
#pragma unroll
        for (int m = 0; m < 4; ++m) A[m] = ldfrag(s_wst, wr * 64 + m * 16 + lo, ks, hi);
#pragma unroll
        for (int n = 0; n < 4; ++n) {
            bf16x8 B = ldfrag(s_act, wc * 64 + n * 16 + lo, ks, hi);
#pragma unroll
            for (int m = 0; m < 4; ++m) g1[m][n] = MFMA16(A[m], B, g1[m][n]);
        }
    }
    __syncthreads();                            // reads done

    stage_w(wsb + 31 * 16384, s_wst, wid, lane);       // Wf2
#pragma unroll
    for (int m = 0; m < 4; ++m)
#pragma unroll
        for (int n = 0; n < 4; ++n) {
            f32x4 v;
#pragma unroll
            for (int r = 0; r < 4; ++r) v[r] = fmaxf(g1[m][n][r], 0.f);
            int col  = wc * 64 + n * 16 + lo;
            int rowb = (wr * 64 + m * 16 + hi * 4) * 2;
            int byte = col * 256 + (rowb ^ ((col & 7) << 4));
            *(u64*)(s_act + byte) = pack4(v);
        }
    __syncthreads();

    // GEMM f2: g2 = Wf2 . g1 + bf2
    f32x4 g2[4][4];
#pragma unroll
    for (int m = 0; m < 4; ++m) {
        f32x4 bv = *(const f32x4*)(bf2 + wr * 64 + m * 16 + hi * 4);
#pragma unroll
        for (int n = 0; n < 4; ++n) g2[m][n] = bv;
    }
#pragma unroll
    for (int ks = 0; ks < 4; ++ks) {
        bf16x8 A[4];
#pragma unroll
        for (int m = 0; m < 4; ++m) A[m] = ldfrag(s_wst, wr * 64 + m * 16 + lo, ks, hi);
#pragma unroll
        for (int n = 0; n < 4; ++n) {
            bf16x8 B = ldfrag(s_act, wc * 64 + n * 16 + lo, ks, hi);
#pragma unroll
            for (int m = 0; m < 4; ++m) g2[m][n] = MFMA16(A[m], B, g2[m][n]);
        }
    }

    // ---- column reduction (mean over T, via per-block partials) ----------
    f32x4 s[4];
#pragma unroll
    for (int m = 0; m < 4; ++m) {
        s[m] = g2[m][0];
#pragma unroll
        for (int n = 1; n < 4; ++n) s[m] += g2[m][n];
    }
#pragma unroll
    for (int m = 0; m < 4; ++m)
#pragma unroll
        for (int r = 0; r < 4; ++r) {
            float v = s[m][r];
            v += __shfl_xor(v, 1, 16);
            v += __shfl_xor(v, 2, 16);
            v += __shfl_xor(v, 4, 16);
            v += __shfl_xor(v, 8, 16);
            s[m][r] = v;
        }
    if (lo == 0) {
#pragma unroll
        for (int m = 0; m < 4; ++m)
#pragma unroll
            for (int r = 0; r < 4; ++r)
                s_red[wc][wr * 64 + m * 16 + hi * 4 + r] = s[m][r];
    }
    __syncthreads();
    if (wc == 0) {
        int row = wr * 64 + lane;
        partial[blk * 128 + row] = s_red[0][row] + s_red[1][row];
    }
}

// ---------------------------------------------------------------------------
// Deterministic final reduce: out[b][c] = (1/T) * sum_j partial[b*256+j][c]
// ---------------------------------------------------------------------------
__global__ void reduce_partials(const float* __restrict__ partial,
                                float* __restrict__ out) {
    int b = blockIdx.x;      // 4
    int c = threadIdx.x;     // 128
    float s = 0.f;
    for (int j = 0; j < 256; ++j) s += partial[(b * 256 + j) * 128 + c];
    out[b * 128 + c] = s * (1.0f / 32768.0f);
}

extern "C" void kernel_launch(void* const* d_in, const int* in_sizes, int n_in,
                              void* d_out, int out_size, void* d_ws, size_t ws_size,
                              hipStream_t stream) {
    const float* x   = (const float*)d_in[0];
    const float* Wd  = (const float*)d_in[1];
    const float* bd  = (const float*)d_in[2];
    const float* Wr  = (const float*)d_in[3];
    const float* br  = (const float*)d_in[4];
    const float* Ws  = (const float*)d_in[5];
    const float* bs  = (const float*)d_in[6];
    const float* Wf1 = (const float*)d_in[7];
    const float* bf1 = (const float*)d_in[8];
    const float* Wf2 = (const float*)d_in[9];
    const float* bf2 = (const float*)d_in[10];

    u16*   wsb     = (u16*)d_ws;                                  // 1 MB bf16 weights
    float* partial = (float*)((char*)d_ws + 32 * 16384 * 2);      // 512 KB partials

    convert_weights<<<2048, 256, 0, stream>>>(Wd, Wr, Ws, Wf1, Wf2, wsb);
    wavenet_main<<<1024, 256, 0, stream>>>(x, wsb, bd, br, bs, bf1, bf2, partial);
    reduce_partials<<<4, 128, 0, stream>>>(partial, (float*)d_out);
}